// Round 5
// baseline (135.762 us; speedup 1.0000x reference)
//
#include <hip/hip_runtime.h>

// LrDistance: out[s,m,n] = invalid ? 100 : |lr[s,m,n] + bilinear(rl[s], gx, gy)|
// grid_sample: padding_mode='zeros', align_corners=False.
//   ix = xr*N/(N-1) - 0.5, xr = n - lr;  iy depends only on m.
// R5: BARRIER-FREE wave-autonomous design. One wave per image row:
//   - wave stages its y-blended rl row into its own 4KB LDS slice
//     (wave-local write->read needs only lgkmcnt, which the compiler inserts;
//     no __syncthreads -> no "s_waitcnt vmcnt(0) before s_barrier" drain that
//     serialized R2-R4 at ~42us with no pipe >40% busy)
//   - per-element: ix via single fma (bilinear continuity makes 1-2ulp floor
//     flips benign; `invalid` still uses bit-exact xr), gather pair via
//     ds_read2-friendly br[xb]/br[xb+1] with +1 pad and edge cndmasks.
// HBM floor: (73.7+49.2)MB / 6.3TB/s ~= 19.5us.

constexpr int S = 16;
constexpr int M = 768;
constexpr int N = 1024;

typedef float vfloat4 __attribute__((ext_vector_type(4)));

__global__ __launch_bounds__(256) void lr_distance_kernel(
    const float* __restrict__ lr,
    const float* __restrict__ rl,
    float* __restrict__ out)
{
    __shared__ float br[4][N + 1];   // one padded row slice per wave

    const int wave = threadIdx.x >> 6;
    const int lane = threadIdx.x & 63;

    // 4 rows per block, blocks never straddle images (M % 4 == 0).
    const int bid   = blockIdx.x;
    const int s     = bid / (M / 4);                 // image index
    const int m     = (bid - s * (M / 4)) * 4 + wave; // row within image
    const int rowid = s * M + m;

    float* brw = br[wave];
    const float* rlp = rl + (size_t)s * M * N;

    // --- y interpolation: wave-uniform (reference op order) ---
    const float gy  = (2.0f * (float)m) / (float)(M - 1) - 1.0f;
    const float iy  = ((gy + 1.0f) * (float)M - 1.0f) * 0.5f;
    const float y0f = floorf(iy);
    const float y1f = y0f + 1.0f;
    const float wy1 = iy - y0f;
    const float wy0 = 1.0f - wy1;
    const bool  y0in = (y0f >= 0.0f) && (y0f <= (float)(M - 1));
    const bool  y1in = (y1f >= 0.0f) && (y1f <= (float)(M - 1));
    const float wy0z = y0in ? wy0 : 0.0f;   // zeros-padding folded into weight
    const float wy1z = y1in ? wy1 : 0.0f;
    const int   y0c  = min(max((int)y0f, 0), M - 1);
    const int   y1c  = min(max((int)y1f, 0), M - 1);
    const float* r0p = rlp + (size_t)y0c * N;
    const float* r1p = rlp + (size_t)y1c * N;

    // --- stage: wave loads both rl rows, blends, writes its LDS slice ---
#pragma unroll
    for (int g = 0; g < 4; ++g) {
        const int idx = (g * 64 + lane) * 4;
        const vfloat4 a = *reinterpret_cast<const vfloat4*>(r0p + idx);
        const vfloat4 b = *reinterpret_cast<const vfloat4*>(r1p + idx);
        const vfloat4 c = wy0z * a + wy1z * b;
        *reinterpret_cast<vfloat4*>(&brw[idx]) = c;
    }
    // no barrier: producer == consumer wave; compiler emits lgkmcnt waits.

    const size_t obase = (size_t)rowid * N;
    const float  C1    = 1024.0f / 1023.0f;   // ix = xr*C1 - 0.5

#pragma unroll
    for (int g = 0; g < 4; ++g) {
        const int n0 = (g * 64 + lane) * 4;
        const vfloat4 d4 = *reinterpret_cast<const vfloat4*>(lr + obase + n0);
        const float dv[4] = {d4.x, d4.y, d4.z, d4.w};
        float ov[4];

#pragma unroll
        for (int k = 0; k < 4; ++k) {
            const float d  = dv[k];
            const float xr = (float)(n0 + k) - d;       // bit-exact vs reference
            const float ix = fmaf(xr, C1, -0.5f);
            const float x0f = floorf(ix);
            const float wx1 = ix - x0f;
            const float wx0 = 1.0f - wx1;
            const int   x0  = (int)x0f;                  // x0 >= -1 when xr >= ~0
            const int   xb  = min(max(x0, 0), N - 1);    // pair base (v_med3)
            const float p0  = brw[xb];
            const float p1  = brw[xb + 1];               // pad covers xb = N-1
            const bool  x0in = (x0 >= 0);
            const bool  x1in = (x0 + 1 <= N - 1);
            const float a  = x0in ? p0 : 0.0f;
            float       bv = x0in ? p1 : p0;             // x0 = -1 -> x1 = 0 -> p0
            bv = x1in ? bv : 0.0f;
            const float warped = wx0 * a + wx1 * bv;

            const bool valid = (xr >= 0.0f) && (xr < (float)N);
            ov[k] = valid ? fabsf(d + warped) : 100.0f;
        }

        vfloat4 o4;
        o4.x = ov[0]; o4.y = ov[1]; o4.z = ov[2]; o4.w = ov[3];
        __builtin_nontemporal_store(o4, reinterpret_cast<vfloat4*>(out + obase + n0));
    }
}

extern "C" void kernel_launch(void* const* d_in, const int* in_sizes, int n_in,
                              void* d_out, int out_size, void* d_ws, size_t ws_size,
                              hipStream_t stream) {
    const float* lr  = (const float*)d_in[0];   // disps_lr [16,1,768,1024] fp32
    const float* rl  = (const float*)d_in[1];   // disps_rl [16,1,768,1024] fp32
    float*       out = (float*)d_out;

    const int blocks  = S * M / 4;   // one wave per row, 4 waves/block: 3072
    const int threads = 256;

    lr_distance_kernel<<<blocks, threads, 0, stream>>>(lr, rl, out);
}